// Round 15
// baseline (97.262 us; speedup 1.0000x reference)
//
#include <hip/hip_runtime.h>
#include <hip/hip_bf16.h>

#define NL    64
#define DIN   512
#define DOUT  512
#define BATCH 1024

#define BM 256
#define BN 256
#define BK 32
#define NK (DIN / BK)   // 16
#define LDSS 40         // padded row stride in shorts (80 B)

typedef short short8 __attribute__((ext_vector_type(8)));
typedef float f32x4  __attribute__((ext_vector_type(4)));

__device__ __forceinline__ unsigned int pk2(float a, float b) {
    // v_cvt_pk_bf16_f32 (RNE)
    __hip_bfloat162 h = __float22bfloat162_rn(make_float2(a, b));
    unsigned int r;
    __builtin_memcpy(&r, &h, 4);
    return r;
}

__global__ __launch_bounds__(512, 2) void nlinear_kernel(
        const float* __restrict__ x, const float* __restrict__ w,
        const float* __restrict__ bias, float* __restrict__ out) {
    // Double-buffered bf16 tiles [row][k], stride 40 shorts (80 B).
    // A: plain pad layout. B: 8B-slot XOR swizzle: quad q of col c at
    // slot q ^ ((c>>2)&7).
    __shared__ unsigned short As[2][BM * LDSS];   // 2 x 20 KB
    __shared__ unsigned short Bs[2][BN * LDSS];   // 2 x 20 KB

    const int tid = threadIdx.x;
    const int bid = blockIdx.x;
    // XCD swizzle: 512 blocks = 8 XCDs x 64; each XCD owns 8 whole layers.
    const int nb    = (bid & 7) * 64 + (bid >> 3);
    const int layer = nb >> 3;
    const int t8    = nb & 7;
    const int bm0   = (t8 & 3) * BM;
    const int bn0   = (t8 >> 2) * BN;

    const int wid  = tid >> 6;
    const int lane = tid & 63;
    const int wr   = wid >> 2, wc = wid & 3;   // 2M x 4N waves, 128x64 each
    const int lrow = lane & 15;
    const int lkb  = lane >> 4;                // k-octet 0..3

    // A-stage: 8 lanes/row (ak*4 floats), rows ar + 64p
    const int ar = tid >> 3;            // 0..63
    const int ak = tid & 7;
    // B-stage: wave gw owns k-quad gw; lane gc owns 4 cols
    const int gw = tid >> 6;            // 0..7
    const int gc = tid & 63;            // 0..63

    const size_t XS = (size_t)NL * DIN;
    const float* xb = x + (size_t)bm0 * XS + (size_t)layer * DIN;
    const float* wb = w + (size_t)layer * DIN * DOUT + bn0;
    const float* aptr0 = xb + (size_t)ar * XS + ak * 4;
    const float* bptr0 = wb + (size_t)(gw * 4) * DOUT + gc * 4;

    f32x4 acc[8][4];
#pragma unroll
    for (int i = 0; i < 8; ++i)
#pragma unroll
        for (int j = 0; j < 4; ++j) acc[i][j] = (f32x4){0.f, 0.f, 0.f, 0.f};

    // 2-interval-deep flights for BOTH operands (16 loads/thread in flight)
    f32x4 avE[4], avO[4], bvE[4], bvO[4];

    auto issueA = [&](int kt, f32x4 (&s)[4]) {
#pragma unroll
        for (int p = 0; p < 4; ++p)
            s[p] = *reinterpret_cast<const f32x4*>(
                aptr0 + (size_t)(64 * p) * XS + kt * BK);
    };
    auto issueB = [&](int kt, f32x4 (&s)[4]) {
#pragma unroll
        for (int p = 0; p < 4; ++p)
            s[p] = *reinterpret_cast<const f32x4*>(
                bptr0 + (size_t)(kt * BK + p) * DOUT);
    };

    auto cvtwriteA = [&](int db, f32x4 (&s)[4]) {
#pragma unroll
        for (int p = 0; p < 4; ++p) {
            uint2 wv;
            wv.x = pk2(s[p][0], s[p][1]);
            wv.y = pk2(s[p][2], s[p][3]);
            *reinterpret_cast<uint2*>(
                &As[db][(ar + 64 * p) * LDSS + ak * 4]) = wv;
        }
    };
    auto cvtwriteB = [&](int db, f32x4 (&s)[4]) {
#pragma unroll
        for (int j = 0; j < 4; ++j) {
            const int c = gc * 4 + j;
            uint2 wv;
            wv.x = pk2(s[0][j], s[1][j]);
            wv.y = pk2(s[2][j], s[3][j]);
            const int slot = gw ^ ((c >> 2) & 7);
            *reinterpret_cast<uint2*>(
                &Bs[db][c * LDSS + slot * 4]) = wv;
        }
    };

    auto fragA = [&](int db, short8* af) {
#pragma unroll
        for (int mi = 0; mi < 8; ++mi) {
            const int row = wr * 128 + mi * 16 + lrow;
            af[mi] = *reinterpret_cast<const short8*>(
                &As[db][row * LDSS + lkb * 8]);
        }
    };
    auto fragB = [&](int db, short8* bf) {
#pragma unroll
        for (int ni = 0; ni < 4; ++ni) {
            const int col = wc * 64 + ni * 16 + lrow;
            const int key = (col >> 2) & 7;
            const unsigned short* base = &Bs[db][col * LDSS];
            uint2 lo = *reinterpret_cast<const uint2*>(
                base + (((2 * lkb) ^ key) << 2));
            uint2 hi = *reinterpret_cast<const uint2*>(
                base + (((2 * lkb + 1) ^ key) << 2));
            uint4 u = make_uint4(lo.x, lo.y, hi.x, hi.y);
            __builtin_memcpy(&bf[ni], &u, 16);
        }
    };

#define BARRIER() do { \
        asm volatile("s_waitcnt lgkmcnt(0)" ::: "memory"); \
        __builtin_amdgcn_sched_barrier(0); \
        __builtin_amdgcn_s_barrier(); \
        __builtin_amdgcn_sched_barrier(0); } while (0)

#define COMPUTE(DB, AF, BF) do { \
        fragA(DB, AF); \
        fragB(DB, BF); \
        asm volatile("s_waitcnt lgkmcnt(0)" ::: "memory"); \
        __builtin_amdgcn_sched_barrier(0); \
        __builtin_amdgcn_s_setprio(1); \
        _Pragma("unroll") \
        for (int mi = 0; mi < 8; ++mi) \
        _Pragma("unroll") \
            for (int ni = 0; ni < 4; ++ni) \
                acc[mi][ni] = __builtin_amdgcn_mfma_f32_16x16x32_bf16( \
                    AF[mi], BF[ni], acc[mi][ni], 0, 0, 0); \
        __builtin_amdgcn_s_setprio(0); \
        __builtin_amdgcn_sched_barrier(0); } while (0)

    // ---- prologue: tile0 staged; tiles 1 (O) and 2 (E) in flight ----
    issueA(0, avE); issueB(0, bvE);
    cvtwriteA(0, avE); cvtwriteB(0, bvE);   // waits tile0 only (nothing newer)
    issueA(1, avO); issueB(1, bvO);
    issueA(2, avE); issueB(2, bvE);
    BARRIER();

    // ---- steady state: cvtwrite consumes 2-interval-old sets ----
    // At cvtwrite(tile k+1), tile k+2's 8 loads are newer -> vmcnt(8),
    // never a full drain; issue tile k+3 afterwards.
#pragma unroll 1
    for (int k = 0; k < NK - 2; k += 2) {
        {   // even tile k: buf0; stage k+1 from O sets; issue k+3 -> O
            short8 af[8], bf[4];
            COMPUTE(0, af, bf);
            cvtwriteA(1, avO);
            cvtwriteB(1, bvO);
            issueA(k + 3, avO);            // k<=12 -> k+3<=15 valid
            issueB(k + 3, bvO);
            BARRIER();
        }
        {   // odd tile k+1: buf1; stage k+2 from E sets; issue k+4 -> E
            short8 af[8], bf[4];
            COMPUTE(1, af, bf);
            cvtwriteA(0, avE);
            cvtwriteB(0, bvE);
            if (k + 4 < NK) { issueA(k + 4, avE); issueB(k + 4, bvE); }
            BARRIER();
        }
    }
    // ---- tile NK-2 (buf0): stage last tile (NK-1) from O sets ----
    {
        short8 af[8], bf[4];
        COMPUTE(0, af, bf);
        cvtwriteA(1, avO);
        cvtwriteB(1, bvO);
        BARRIER();
    }
    // ---- tile NK-1 (buf1): compute only ----
    {
        short8 af[8], bf[4];
        COMPUTE(1, af, bf);
    }

    // ---- epilogue: + bias, fp32 store ----
    const float* bb = bias + (size_t)layer * DOUT + bn0;
    float* ob = out + (size_t)bm0 * (NL * DOUT) + (size_t)layer * DOUT + bn0;
#pragma unroll
    for (int mi = 0; mi < 8; ++mi) {
#pragma unroll
        for (int ni = 0; ni < 4; ++ni) {
            const int col = wc * 64 + ni * 16 + lrow;
            const float bval = bb[col];
#pragma unroll
            for (int r = 0; r < 4; ++r) {
                const int row = wr * 128 + mi * 16 + lkb * 4 + r;
                ob[(size_t)row * (NL * DOUT) + col] = acc[mi][ni][r] + bval;
            }
        }
    }
#undef BARRIER
#undef COMPUTE
}

extern "C" void kernel_launch(void* const* d_in, const int* in_sizes, int n_in,
                              void* d_out, int out_size, void* d_ws, size_t ws_size,
                              hipStream_t stream) {
    const float* x  = (const float*)d_in[0];
    const float* w  = (const float*)d_in[1];
    const float* b  = (const float*)d_in[2];
    float* out      = (float*)d_out;

    dim3 grid(NL * (BATCH / BM) * (DOUT / BN));   // 64 * 4 * 2 = 512
    dim3 block(512);
    hipLaunchKernelGGL(nlinear_kernel, grid, block, 0, stream, x, w, b, out);
}